// Round 1
// baseline (192.857 us; speedup 1.0000x reference)
//
#include <hip/hip_runtime.h>

#define DD 8
#define HH 512
#define WW 512
#define HWs (HH * WW)
#define DHWs (DD * HWs)
#define BCs 8
#define NITERS 5

// Solve the 3x3 symmetric system at interior position (di,hi,wi) of one (b,c) volume.
// Returns false when |det| <= 1e-7 (reference's sol_f).
__device__ __forceinline__ bool solve_at(const float* __restrict__ xb,
                                         int di, int hi, int wi,
                                         float& sx, float& sy, float& ss, float& gds)
{
    const float* p = xb + (size_t)di * HWs + (size_t)hi * WW + wi;
    float v   = p[0];
    float xpw = p[1],         xmw = p[-1];
    float xph = p[WW],        xmh = p[-WW];
    float xpd = p[HWs],       xmd = p[-HWs];
    float g1  = p[WW + 1],    g2  = p[WW - 1],    g3 = p[-WW + 1],   g4 = p[-WW - 1];
    float h1  = p[HWs + 1],   h2  = p[HWs - 1],   h3 = p[-HWs + 1],  h4 = p[-HWs - 1];
    float i1  = p[HWs + WW],  i2  = p[HWs - WW],  i3 = p[-HWs + WW], i4 = p[-HWs - WW];

    float gx = 0.5f * (xpw - xmw);
    float gy = 0.5f * (xph - xmh);
    float gs = 0.5f * (xpd - xmd);
    float dxx = xpw + xmw - 2.0f * v;
    float dyy = xph + xmh - 2.0f * v;
    float dss = xpd + xmd - 2.0f * v;
    float dxy = 0.25f * (g1 - g2 - g3 + g4);
    float dxs = 0.25f * (h1 - h2 - h3 + h4);
    float dys = 0.25f * (i1 - i2 - i3 + i4);

    float r0 = -gx, r1 = -gy, r2 = -gs;
    float cf00 = dyy * dss - dys * dys;
    float cf01 = dxy * dss - dys * dxs;
    float cf02 = dxy * dys - dyy * dxs;
    float det  = dxx * cf00 - dxy * cf01 + dxs * cf02;
    if (!(fabsf(det) > 1e-7f)) return false;

    float t0 = r1 * dss - dys * r2;
    float t1 = r1 * dys - dyy * r2;
    float t2 = dxy * r2 - r1 * dxs;
    float t3 = dyy * r2 - r1 * dys;
    sx = (r0 * cf00 - dxy * t0 + dxs * t1) / det;
    sy = (dxx * t0 - r0 * cf01 + dxs * t2) / det;
    ss = (dxx * t3 - dxy * t2 + r0 * cf02) / det;
    gds = gx * sx + gy * sy + gs * ss;
    return true;
}

__global__ __launch_bounds__(256) void cqi_kernel(const float* __restrict__ x,
                                                  float* __restrict__ out)
{
    int tid = blockIdx.x * 256 + threadIdx.x;
    int w  = tid & (WW - 1);
    int h  = (tid >> 9) & (HH - 1);
    int bc = tid >> 18;

    const float* xb = x + (size_t)bc * DHWs;

    // clamp-to-edge == -inf padding for windowed max (duplicates in-window values)
    int hm = h > 0 ? h - 1 : 0, hp = h < HH - 1 ? h + 1 : HH - 1;
    int wm = w > 0 ? w - 1 : 0, wp = w < WW - 1 ? w + 1 : WW - 1;

    float m2[DD];   // per-slice 3x3 in-plane max
    float cen[DD];  // center values
    #pragma unroll
    for (int d = 0; d < DD; ++d) {
        const float* s  = xb + (size_t)d * HWs;
        const float* r0 = s + (size_t)hm * WW;
        const float* r1 = s + (size_t)h  * WW;
        const float* r2 = s + (size_t)hp * WW;
        float m = fmaxf(fmaxf(r0[wm], r0[w]), r0[wp]);
        m = fmaxf(m, fmaxf(fmaxf(r1[wm], r1[w]), r1[wp]));
        m = fmaxf(m, fmaxf(fmaxf(r2[wm], r2[w]), r2[wp]));
        m2[d]  = m;
        cen[d] = r1[w];
    }

    float* ybase = out + (size_t)BCs * 3 * DHWs;

    #pragma unroll
    for (int d = 0; d < DD; ++d) {
        int dm = d > 0 ? d - 1 : 0;
        int dp = d < DD - 1 ? d + 1 : DD - 1;
        float mx = fmaxf(fmaxf(m2[dm], m2[d]), m2[dp]);
        bool nms = (cen[d] == mx);

        float cs = (float)d, cx = (float)w, cy = (float)h;
        float yv = cen[d];

        if (nms) {
            yv += 10.0f;  // strict_maxima_bonus
            int cd = d, chh = h, cw = w;
            bool valid = true;
            float shx = 0.f, shy = 0.f, shs = 0.f, gds = 0.f;
            for (int it = 0; it < NITERS; ++it) {
                int di = cd  < 1 ? 1 : (cd  > DD - 2 ? DD - 2 : cd);
                int hi = chh < 1 ? 1 : (chh > HH - 2 ? HH - 2 : chh);
                int wi = cw  < 1 ? 1 : (cw  > WW - 2 ? WW - 2 : cw);
                float sx, sy, ss, g;
                if (!solve_at(xb, di, hi, wi, sx, sy, ss, g)) { valid = false; break; }
                shx = sx; shy = sy; shs = ss; gds = g;
                int mvw = (fabsf(sx) > 0.6f) ? (sx > 0.f ? 1 : -1) : 0;
                int mvh = (fabsf(sy) > 0.6f) ? (sy > 0.f ? 1 : -1) : 0;
                int mvd = (fabsf(ss) > 0.6f) ? (ss > 0.f ? 1 : -1) : 0;
                if ((mvw | mvh | mvd) == 0) break;  // fixed point, valid stays true
                cw += mvw; chh += mvh; cd += mvd;
                int ad = cd - d;  if (ad < 0) ad = -ad;
                int ah = chh - h; if (ah < 0) ah = -ah;
                int aw = cw - w;  if (aw < 0) aw = -aw;
                if (ad > 1 || ah > 1 || aw > 1) { valid = false; break; }
            }
            if (valid) {
                cs = (float)cd  + shs;
                cx = (float)cw  + shx;
                cy = (float)chh + shy;
                yv += 0.5f * gds;
            }
        }

        size_t sp = (size_t)d * HWs + (size_t)h * WW + w;
        out[((size_t)bc * 3 + 0) * DHWs + sp] = cs;
        out[((size_t)bc * 3 + 1) * DHWs + sp] = cx;
        out[((size_t)bc * 3 + 2) * DHWs + sp] = cy;
        ybase[(size_t)bc * DHWs + sp] = yv;
    }
}

extern "C" void kernel_launch(void* const* d_in, const int* in_sizes, int n_in,
                              void* d_out, int out_size, void* d_ws, size_t ws_size,
                              hipStream_t stream)
{
    const float* x = (const float*)d_in[0];
    float* out = (float*)d_out;
    int total_threads = BCs * HH * WW;           // 2,097,152
    dim3 grid(total_threads / 256), block(256);  // 8192 blocks
    hipLaunchKernelGGL(cqi_kernel, grid, block, 0, stream, x, out);
}